// Round 9
// baseline (207.180 us; speedup 1.0000x reference)
//
#include <hip/hip_runtime.h>

typedef unsigned short u16;
typedef unsigned int   u32;

using bf16x8 = __attribute__((ext_vector_type(8))) __bf16;
using f32x4  = __attribute__((ext_vector_type(4))) float;
using s16x4  = __attribute__((ext_vector_type(4))) short;

#define NH    16
#define DKH   64
#define SEQ   2048
#define BAT   2
#define DMOD  1024

// 0.125 (1/sqrt(dk)) * log2(e): scores in log2 domain -> p = exp2(s)
#define QSCALE 0.18033688011112042f

__device__ __forceinline__ u16 f2bf(float f) {
  union { float f; u32 u; } v; v.f = f;
  u32 r = v.u + 0x7fffu + ((v.u >> 16) & 1u);
  return (u16)(r >> 16);
}

__device__ __forceinline__ u32 pack2bf(float a, float b) {
  union { float f; u32 u; } x, y; x.f = a; y.f = b;
  u32 ua = x.u + 0x7fffu + ((x.u >> 16) & 1u);
  u32 ub = y.u + 0x7fffu + ((y.u >> 16) & 1u);
  return __builtin_amdgcn_perm(ub, ua, 0x07060302u);
}

__device__ __forceinline__ void gll16(const u16* g, u16* l) {
  __builtin_amdgcn_global_load_lds((__attribute__((address_space(1))) void*)(u16*)g,
                                   (__attribute__((address_space(3))) void*)l,
                                   16, 0, 0);
}

#if __has_builtin(__builtin_amdgcn_exp2f)
#define EXP2(x) __builtin_amdgcn_exp2f(x)
#else
#define EXP2(x) exp2f(x)
#endif

#if __has_builtin(__builtin_amdgcn_mfma_f32_16x16x16bf16_1k)
__device__ __forceinline__ f32x4 mfma16(s16x4 a, s16x4 b, f32x4 c) {
  return __builtin_amdgcn_mfma_f32_16x16x16bf16_1k(a, b, c, 0, 0, 0);
}
#else
__device__ __forceinline__ f32x4 mfma16(s16x4 a, s16x4 b, f32x4 c) {
  f32x4 d;
  asm volatile("v_mfma_f32_16x16x16_bf16 %0, %1, %2, %3\n\ts_nop 7\n\ts_nop 7"
               : "=v"(d) : "v"(a), "v"(b), "v"(c));
  return d;
}
#endif

// ---------------- fused 4x weight transpose + fp32->bf16 ----------------
__global__ __launch_bounds__(256) void transpose_all(const float* __restrict__ Wq,
                                                     const float* __restrict__ Wk,
                                                     const float* __restrict__ Wv,
                                                     const float* __restrict__ Wo,
                                                     u16* __restrict__ Wt) {
  __shared__ u16 t[32][33];
  const float* W = blockIdx.z == 0 ? Wq : blockIdx.z == 1 ? Wk : blockIdx.z == 2 ? Wv : Wo;
  u16* o = Wt + (size_t)blockIdx.z * DMOD * DMOD;
  int bx = blockIdx.x * 32, by = blockIdx.y * 32;
  int x = threadIdx.x, y = threadIdx.y;
  #pragma unroll
  for (int i = 0; i < 32; i += 8)
    t[y + i][x] = f2bf(W[(size_t)(by + y + i) * DMOD + bx + x]);
  __syncthreads();
  #pragma unroll
  for (int i = 0; i < 32; i += 8)
    o[(size_t)(bx + y + i) * DMOD + by + x] = t[x][y + i];
}

// ---------------- x fp32 -> bf16 ----------------
__global__ __launch_bounds__(256) void convert_x(const float* __restrict__ x,
                                                 u16* __restrict__ xb) {
  size_t i = ((size_t)blockIdx.x * 256 + threadIdx.x) * 8;
  float4 f0 = *(const float4*)(x + i);
  float4 f1 = *(const float4*)(x + i + 4);
  uint4 o;
  o.x = pack2bf(f0.x, f0.y); o.y = pack2bf(f0.z, f0.w);
  o.z = pack2bf(f1.x, f1.y); o.w = pack2bf(f1.z, f1.w);
  *(uint4*)(xb + i) = o;
}

// ---------------- QKV GEMM: [4096 x 1024] * [3072 x 1024]^T, BK=64, swizzled LDS -------
__global__ __launch_bounds__(256) void gemm_qkv(const u16* __restrict__ A,
                                                const u16* __restrict__ Bt,
                                                u16* __restrict__ Qo,
                                                u16* __restrict__ Ko,
                                                u16* __restrict__ Vo) {
  __shared__ __align__(16) u16 As[128 * 64];
  __shared__ __align__(16) u16 Bs[128 * 64];
  const int tid  = threadIdx.x;
  const int lane = tid & 63, wv = tid >> 6;
  const int wm   = wv >> 1, wn = wv & 1;
  const int lrow = lane & 15, quad = lane >> 4;
  const int sw   = lrow & 7;
  const int tileM = blockIdx.x * 128, tileN = blockIdx.y * 128;
  const int srow8 = lane >> 3;
  const int scc   = ((lane & 7) ^ srow8) * 8;

  const f32x4 fz = {0.f, 0.f, 0.f, 0.f};
  f32x4 acc[4][4];
  #pragma unroll
  for (int i = 0; i < 4; ++i)
    #pragma unroll
    for (int j = 0; j < 4; ++j) acc[i][j] = fz;

  for (int kt = 0; kt < DMOD; kt += 64) {
    #pragma unroll
    for (int i = 0; i < 4; ++i) {
      int rb = wv * 32 + i * 8;
      gll16(&A [(size_t)(tileM + rb + srow8) * DMOD + kt + scc], &As[rb * 64]);
      gll16(&Bt[(size_t)(tileN + rb + srow8) * DMOD + kt + scc], &Bs[rb * 64]);
    }
    __syncthreads();
    #pragma unroll
    for (int kk = 0; kk < 2; ++kk) {
      bf16x8 af[4], bfr[4];
      #pragma unroll
      for (int mt = 0; mt < 4; ++mt)
        af[mt] = *(const bf16x8*)(&As[(wm * 64 + mt * 16 + lrow) * 64 +
                                      (((kk * 4 + quad) ^ sw) * 8)]);
      #pragma unroll
      for (int nt = 0; nt < 4; ++nt)
        bfr[nt] = *(const bf16x8*)(&Bs[(wn * 64 + nt * 16 + lrow) * 64 +
                                       (((kk * 4 + quad) ^ sw) * 8)]);
      #pragma unroll
      for (int mt = 0; mt < 4; ++mt)
        #pragma unroll
        for (int nt = 0; nt < 4; ++nt)
          acc[mt][nt] = __builtin_amdgcn_mfma_f32_16x16x32_bf16(af[mt], bfr[nt],
                                                                acc[mt][nt], 0, 0, 0);
    }
    __syncthreads();
  }

  #pragma unroll
  for (int mt = 0; mt < 4; ++mt) {
    #pragma unroll
    for (int nt = 0; nt < 4; ++nt) {
      int gm0 = tileM + wm * 64 + mt * 16 + quad * 4;
      int gn  = tileN + wn * 64 + nt * 16 + lrow;
      int which = gn >> 10, col = gn & 1023;
      int bb = gm0 >> 11, srw0 = gm0 & (SEQ - 1);
      int hh = col >> 6, dki = col & (DKH - 1);
      size_t bhi = (size_t)(bb * NH + hh);
      if (which == 0) {
        #pragma unroll
        for (int r = 0; r < 4; ++r)
          Qo[(bhi * SEQ + srw0 + r) * DKH + dki] = f2bf(acc[mt][nt][r] * QSCALE);
      } else if (which == 1) {
        #pragma unroll
        for (int r = 0; r < 4; ++r)
          Ko[(bhi * SEQ + srw0 + r) * DKH + dki] = f2bf(acc[mt][nt][r]);
      } else {
        uint2 pk;
        pk.x = pack2bf(acc[mt][nt][0], acc[mt][nt][1]);
        pk.y = pack2bf(acc[mt][nt][2], acc[mt][nt][3]);
        *(uint2*)(&Vo[(((bhi * (SEQ / 4)) + (srw0 >> 2)) * DKH + dki) * 4]) = pk;
      }
    }
  }
}

// ---------------- out GEMM: [4096x1024]*[1024x1024]^T -> fp32, 128x64 tiles, BK=64 ------
__global__ __launch_bounds__(256) void gemm_out(const u16* __restrict__ A,
                                                const u16* __restrict__ Bt,
                                                float* __restrict__ Co) {
  __shared__ __align__(16) u16 As[128 * 64];
  __shared__ __align__(16) u16 Bs[64 * 64];
  const int tid  = threadIdx.x;
  const int lane = tid & 63, wv = tid >> 6;
  const int wm   = wv & 1, wn = wv >> 1;
  const int lrow = lane & 15, quad = lane >> 4;
  const int sw   = lrow & 7;
  const int tileM = blockIdx.x * 128, tileN = blockIdx.y * 64;
  const int srow8 = lane >> 3;
  const int scc   = ((lane & 7) ^ srow8) * 8;

  const f32x4 fz = {0.f, 0.f, 0.f, 0.f};
  f32x4 acc[4][2];
  #pragma unroll
  for (int i = 0; i < 4; ++i) { acc[i][0] = fz; acc[i][1] = fz; }

  for (int kt = 0; kt < DMOD; kt += 64) {
    #pragma unroll
    for (int i = 0; i < 4; ++i) {
      int rb = wv * 32 + i * 8;
      gll16(&A[(size_t)(tileM + rb + srow8) * DMOD + kt + scc], &As[rb * 64]);
    }
    #pragma unroll
    for (int i = 0; i < 2; ++i) {
      int rb = wv * 16 + i * 8;
      gll16(&Bt[(size_t)(tileN + rb + srow8) * DMOD + kt + scc], &Bs[rb * 64]);
    }
    __syncthreads();
    #pragma unroll
    for (int kk = 0; kk < 2; ++kk) {
      bf16x8 af[4], bfr[2];
      #pragma unroll
      for (int mt = 0; mt < 4; ++mt)
        af[mt] = *(const bf16x8*)(&As[(wm * 64 + mt * 16 + lrow) * 64 +
                                      (((kk * 4 + quad) ^ sw) * 8)]);
      #pragma unroll
      for (int nt = 0; nt < 2; ++nt)
        bfr[nt] = *(const bf16x8*)(&Bs[(wn * 32 + nt * 16 + lrow) * 64 +
                                       (((kk * 4 + quad) ^ sw) * 8)]);
      #pragma unroll
      for (int mt = 0; mt < 4; ++mt)
        #pragma unroll
        for (int nt = 0; nt < 2; ++nt)
          acc[mt][nt] = __builtin_amdgcn_mfma_f32_16x16x32_bf16(af[mt], bfr[nt],
                                                                acc[mt][nt], 0, 0, 0);
    }
    __syncthreads();
  }

  #pragma unroll
  for (int mt = 0; mt < 4; ++mt)
    #pragma unroll
    for (int nt = 0; nt < 2; ++nt)
      #pragma unroll
      for (int r = 0; r < 4; ++r) {
        int gm = tileM + wm * 64 + mt * 16 + quad * 4 + r;
        int gn = tileN + wn * 32 + nt * 16 + lrow;
        Co[(size_t)gm * DMOD + gn] = acc[mt][nt][r];
      }
}

// ------- causal flash attention, K-range-split (flash-decoding): partial O + l --------
// grid (32 bh, 16 qt, 2 s); block 512 = 8 waves. Block (bh,qt,s) covers k-tiles
// j in [j0,j1): s=0 -> [0, (qt+2)/2), s=1 -> [(qt+2)/2, qt+1). No-max log2 softmax makes
// partials combine linearly: O = (O0+O1)/(l0+l1) -- done by combine_k. Single-buffered
// LDS (35 KB) + launch_bounds(512,4) -> 2 blocks/CU co-resident; 1024 blocks backfill.
// Partials: Opart[p][row][dk] fp32 (unnormalized, C-layout float4 stores), lpart[p][row],
// p = s*512 + bh*16 + qt.
#define KP 72
#define VP 132

__global__ __launch_bounds__(512, 4) void attn_k(const u16* __restrict__ Q,
                                                 const u16* __restrict__ Kg,
                                                 const u16* __restrict__ Vg,
                                                 float* __restrict__ Opart,
                                                 float* __restrict__ lpart) {
  __shared__ __align__(16) u16 Ks[128 * KP];
  __shared__ __align__(16) u16 Vs[64 * VP];

  const int tid  = threadIdx.x;
  const int lane = tid & 63, w = tid >> 6;
  const int lrow = lane & 15, quad = lane >> 4;
  const int bh = blockIdx.x, qt = blockIdx.y, s = blockIdx.z;
  const int split = (qt + 2) >> 1;
  const int j0 = s ? split : 0;
  const int j1 = s ? (qt + 1) : split;

  const int p = s * 512 + bh * 16 + qt;
  float* Op = Opart + (size_t)p * (128 * 64);

  if (j0 >= j1) {   // empty upper range (qt==0,s==1): write zero partials
    const f32x4 fz = {0.f, 0.f, 0.f, 0.f};
    for (int t = tid; t < 128 * 64 / 4; t += 512) ((f32x4*)Op)[t] = fz;
    if (tid < 128) lpart[(size_t)p * 128 + tid] = 0.f;
    return;
  }

  const u16* Qbh = Q  + (size_t)bh * SEQ * DKH;
  const u16* Kbh = Kg + (size_t)bh * SEQ * DKH;
  const u16* Vbh = Vg + (size_t)bh * SEQ * DKH;   // [s/4][dk][4]

  const int qglob = qt * 128 + w * 16 + lrow;
  bf16x8 bq[2];
  #pragma unroll
  for (int kk = 0; kk < 2; ++kk)
    bq[kk] = *(const bf16x8*)(&Qbh[(size_t)qglob * DKH + kk * 32 + quad * 8]);

  // prefetch first tile
  uint4 kreg[2], vreg[2];
  #pragma unroll
  for (int k = 0; k < 2; ++k) {
    int ci = k * 512 + tid;
    kreg[k] = *(const uint4*)(&Kbh[(size_t)(j0 * 128 + (ci >> 3)) * DKH + (ci & 7) * 8]);
    vreg[k] = *(const uint4*)(&Vbh[(size_t)(j0 * 32 + (ci >> 5)) * 256 + (ci & 31) * 8]);
  }

  const f32x4 fz = {0.f, 0.f, 0.f, 0.f};
  f32x4 oacc[4];
  #pragma unroll
  for (int d = 0; d < 4; ++d) oacc[d] = fz;
  float lsum = 0.f;

  for (int j = j0; j < j1; ++j) {
    __syncthreads();   // everyone done reading previous tile
    #pragma unroll
    for (int k = 0; k < 2; ++k) {
      int ci = k * 512 + tid;
      *(uint4*)(&Ks[(ci >> 3) * KP + (ci & 7) * 8]) = kreg[k];
      int sq = ci >> 5, dkp = ci & 31;
      union { uint4 q; uint2 d[2]; } vv; vv.q = vreg[k];
      *(uint2*)(&Vs[(2 * dkp)     * VP + 4 * sq]) = vv.d[0];
      *(uint2*)(&Vs[(2 * dkp + 1) * VP + 4 * sq]) = vv.d[1];
    }
    if (j + 1 < j1) {
      #pragma unroll
      for (int k = 0; k < 2; ++k) {
        int ci = k * 512 + tid;
        kreg[k] = *(const uint4*)(&Kbh[(size_t)((j + 1) * 128 + (ci >> 3)) * DKH + (ci & 7) * 8]);
        vreg[k] = *(const uint4*)(&Vbh[(size_t)((j + 1) * 32 + (ci >> 5)) * 256 + (ci & 31) * 8]);
      }
    }
    __syncthreads();   // tile visible

    if (j < qt) {
      // full iteration, straight-line
      f32x4 sacc[8];
      #pragma unroll
      for (int m = 0; m < 8; ++m) sacc[m] = fz;
      #pragma unroll
      for (int kk = 0; kk < 2; ++kk)
        #pragma unroll
        for (int m = 0; m < 8; ++m) {
          bf16x8 ak = *(const bf16x8*)(&Ks[(m * 16 + lrow) * KP + kk * 32 + quad * 8]);
          sacc[m] = __builtin_amdgcn_mfma_f32_16x16x32_bf16(ak, bq[kk], sacc[m], 0, 0, 0);
        }
      #pragma unroll
      for (int m = 0; m < 8; ++m)
        #pragma unroll
        for (int r = 0; r < 4; ++r) {
          float pv = EXP2(sacc[m][r]);
          sacc[m][r] = pv;
          lsum += pv;
        }
      #pragma unroll
      for (int m = 0; m < 8; ++m) {
        union { u32 u[2]; s16x4 v; } pk;
        pk.u[0] = pack2bf(sacc[m][0], sacc[m][1]);
        pk.u[1] = pack2bf(sacc[m][2], sacc[m][3]);
        #pragma unroll
        for (int d = 0; d < 4; ++d) {
          s16x4 av = *(const s16x4*)(&Vs[(d * 16 + lrow) * VP + m * 16 + quad * 4]);
          oacc[d] = mfma16(av, pk.v, oacc[d]);
        }
      }
    } else {
      // diagonal: m<w unmasked, m==w masked, m>w skipped
      for (int m = 0; m < w; ++m) {
        f32x4 sv = fz;
        #pragma unroll
        for (int kk = 0; kk < 2; ++kk) {
          bf16x8 ak = *(const bf16x8*)(&Ks[(m * 16 + lrow) * KP + kk * 32 + quad * 8]);
          sv = __builtin_amdgcn_mfma_f32_16x16x32_bf16(ak, bq[kk], sv, 0, 0, 0);
        }
        union { u32 u[2]; s16x4 v; } pk;
        float p0 = EXP2(sv[0]), p1 = EXP2(sv[1]), p2 = EXP2(sv[2]), p3 = EXP2(sv[3]);
        lsum += (p0 + p1) + (p2 + p3);
        pk.u[0] = pack2bf(p0, p1);
        pk.u[1] = pack2bf(p2, p3);
        #pragma unroll
        for (int d = 0; d < 4; ++d) {
          s16x4 av = *(const s16x4*)(&Vs[(d * 16 + lrow) * VP + m * 16 + quad * 4]);
          oacc[d] = mfma16(av, pk.v, oacc[d]);
        }
      }
      {
        f32x4 sv = fz;
        #pragma unroll
        for (int kk = 0; kk < 2; ++kk) {
          bf16x8 ak = *(const bf16x8*)(&Ks[(w * 16 + lrow) * KP + kk * 32 + quad * 8]);
          sv = __builtin_amdgcn_mfma_f32_16x16x32_bf16(ak, bq[kk], sv, 0, 0, 0);
        }
        float pv[4];
        #pragma unroll
        for (int r = 0; r < 4; ++r) {
          int kg = qt * 128 + w * 16 + quad * 4 + r;
          pv[r] = (kg > qglob) ? 0.f : EXP2(sv[r]);
          lsum += pv[r];
        }
        union { u32 u[2]; s16x4 v; } pk;
        pk.u[0] = pack2bf(pv[0], pv[1]);
        pk.u[1] = pack2bf(pv[2], pv[3]);
        #pragma unroll
        for (int d = 0; d < 4; ++d) {
          s16x4 av = *(const s16x4*)(&Vs[(d * 16 + lrow) * VP + w * 16 + quad * 4]);
          oacc[d] = mfma16(av, pk.v, oacc[d]);
        }
      }
    }
  }

  // partial lsum across quads (disjoint key subsets per q-column)
  float ls = lsum;
  ls += __shfl_xor(ls, 16, 64);
  ls += __shfl_xor(ls, 32, 64);
  if (quad == 0) lpart[(size_t)p * 128 + w * 16 + lrow] = ls;

  // unnormalized O partial, C-layout float4 stores (row-major [row][dk])
  const int row = w * 16 + lrow;
  #pragma unroll
  for (int d = 0; d < 4; ++d)
    *(f32x4*)(&Op[(size_t)row * 64 + d * 16 + quad * 4]) = oacc[d];
}

// ---------------- combine partials: Ob = (O0+O1)/(l0+l1), bf16, [b,s,h*64+dk] ----------
__global__ __launch_bounds__(256) void combine_k(const float* __restrict__ Opart,
                                                 const float* __restrict__ lpart,
                                                 u16* __restrict__ Ob) {
  int t = blockIdx.x * 256 + threadIdx.x;     // 1,048,576 threads: (bh,qt,row,dk4)
  int dk4 = t & 15;
  int row = (t >> 4) & 127;
  int qt  = (t >> 11) & 15;
  int bh  = t >> 15;
  size_t prow0 = ((size_t)(bh * 16 + qt)) * 128 + row;
  size_t prow1 = prow0 + 512 * 128;
  f32x4 a = *(const f32x4*)(&Opart[prow0 * 64 + dk4 * 4]);
  f32x4 b = *(const f32x4*)(&Opart[prow1 * 64 + dk4 * 4]);
  float inv = 1.f / (lpart[prow0] + lpart[prow1]);
  f32x4 c = (a + b) * inv;
  int bb = bh >> 4, h = bh & 15;
  int srow = qt * 128 + row;
  uint2 pk;
  pk.x = pack2bf(c[0], c[1]);
  pk.y = pack2bf(c[2], c[3]);
  *(uint2*)(&Ob[((size_t)(bb * SEQ + srow)) * DMOD + h * DKH + dk4 * 4]) = pk;
}

// ---------------- launch ----------------
extern "C" void kernel_launch(void* const* d_in, const int* in_sizes, int n_in,
                              void* d_out, int out_size, void* d_ws, size_t ws_size,
                              hipStream_t stream) {
  const float* x  = (const float*)d_in[0];
  const float* Wq = (const float*)d_in[1];
  const float* Wk = (const float*)d_in[2];
  const float* Wv = (const float*)d_in[3];
  const float* Wo = (const float*)d_in[4];

  u16* ws = (u16*)d_ws;
  const size_t WSZ = (size_t)DMOD * DMOD;
  const size_t TSZ = (size_t)BAT * NH * SEQ * DKH;
  u16* Wt  = ws;                 // 4 transposed weights (8 MB)
  u16* Wto = Wt + 3 * WSZ;
  u16* xb  = Wt + 4 * WSZ;       // x bf16; dead after QKV -> reused as Ob
  u16* Qb  = xb + TSZ;
  u16* Kb  = Qb + TSZ;
  u16* Vb  = Kb + TSZ;           // [b,h,s/4,dk,4]
  u16* Ob  = xb;
  float* Opart = (float*)(Vb + TSZ);            // 1024 parts x 128 x 64 fp32 (33.6 MB)
  float* lpart = Opart + (size_t)1024 * 128 * 64;  // 1024 x 128 fp32 (0.5 MB)

  transpose_all<<<dim3(32, 32, 4), dim3(32, 8), 0, stream>>>(Wq, Wk, Wv, Wo, Wt);
  convert_x<<<dim3(2048), 256, 0, stream>>>(x, xb);

  gemm_qkv<<<dim3(32, 24), 256, 0, stream>>>(xb, Wt, Qb, Kb, Vb);

  attn_k<<<dim3(32, 16, 2), 512, 0, stream>>>(Qb, Kb, Vb, Opart, lpart);
  combine_k<<<dim3(4096), 256, 0, stream>>>(Opart, lpart, Ob);

  gemm_out<<<dim3(32, 16), 256, 0, stream>>>(Ob, Wto, (float*)d_out);
}

// Round 10
// 185.443 us; speedup vs baseline: 1.1172x; 1.1172x over previous
//
#include <hip/hip_runtime.h>

typedef unsigned short u16;
typedef unsigned int   u32;

using bf16x8 = __attribute__((ext_vector_type(8))) __bf16;
using f32x4  = __attribute__((ext_vector_type(4))) float;
using s16x4  = __attribute__((ext_vector_type(4))) short;

#define NH    16
#define DKH   64
#define SEQ   2048
#define BAT   2
#define DMOD  1024

// 0.125 (1/sqrt(dk)) * log2(e): scores in log2 domain -> p = exp2(s)
#define QSCALE 0.18033688011112042f

__device__ __forceinline__ u16 f2bf(float f) {
  union { float f; u32 u; } v; v.f = f;
  u32 r = v.u + 0x7fffu + ((v.u >> 16) & 1u);
  return (u16)(r >> 16);
}

__device__ __forceinline__ u32 pack2bf(float a, float b) {
  union { float f; u32 u; } x, y; x.f = a; y.f = b;
  u32 ua = x.u + 0x7fffu + ((x.u >> 16) & 1u);
  u32 ub = y.u + 0x7fffu + ((y.u >> 16) & 1u);
  return __builtin_amdgcn_perm(ub, ua, 0x07060302u);
}

#if __has_builtin(__builtin_amdgcn_exp2f)
#define EXP2(x) __builtin_amdgcn_exp2f(x)
#else
#define EXP2(x) exp2f(x)
#endif

#if __has_builtin(__builtin_amdgcn_mfma_f32_16x16x16bf16_1k)
__device__ __forceinline__ f32x4 mfma16(s16x4 a, s16x4 b, f32x4 c) {
  return __builtin_amdgcn_mfma_f32_16x16x16bf16_1k(a, b, c, 0, 0, 0);
}
#else
__device__ __forceinline__ f32x4 mfma16(s16x4 a, s16x4 b, f32x4 c) {
  f32x4 d;
  asm volatile("v_mfma_f32_16x16x16_bf16 %0, %1, %2, %3\n\ts_nop 7\n\ts_nop 7"
               : "=v"(d) : "v"(a), "v"(b), "v"(c));
  return d;
}
#endif

// ---------------- fused 4x weight transpose + fp32->bf16 ----------------
__global__ __launch_bounds__(256) void transpose_all(const float* __restrict__ Wq,
                                                     const float* __restrict__ Wk,
                                                     const float* __restrict__ Wv,
                                                     const float* __restrict__ Wo,
                                                     u16* __restrict__ Wt) {
  __shared__ u16 t[32][33];
  const float* W = blockIdx.z == 0 ? Wq : blockIdx.z == 1 ? Wk : blockIdx.z == 2 ? Wv : Wo;
  u16* o = Wt + (size_t)blockIdx.z * DMOD * DMOD;
  int bx = blockIdx.x * 32, by = blockIdx.y * 32;
  int x = threadIdx.x, y = threadIdx.y;
  #pragma unroll
  for (int i = 0; i < 32; i += 8)
    t[y + i][x] = f2bf(W[(size_t)(by + y + i) * DMOD + bx + x]);
  __syncthreads();
  #pragma unroll
  for (int i = 0; i < 32; i += 8)
    o[(size_t)(bx + y + i) * DMOD + by + x] = t[x][y + i];
}

// ---------------- x fp32 -> bf16 ----------------
__global__ __launch_bounds__(256) void convert_x(const float* __restrict__ x,
                                                 u16* __restrict__ xb) {
  size_t i = ((size_t)blockIdx.x * 256 + threadIdx.x) * 8;
  float4 f0 = *(const float4*)(x + i);
  float4 f1 = *(const float4*)(x + i + 4);
  uint4 o;
  o.x = pack2bf(f0.x, f0.y); o.y = pack2bf(f0.z, f0.w);
  o.z = pack2bf(f1.x, f1.y); o.w = pack2bf(f1.z, f1.w);
  *(uint4*)(xb + i) = o;
}

// -------- QKV GEMM: [4096x1024]*[3072x1024]^T, BK=32, reg-prefetch, padded LDS --------
// Per iter: barrier -> ds_write regs (tile k) -> issue global loads (tile k+1) ->
// barrier -> compute. HBM/L2 latency of k+1 overlaps compute of k (not the barrier).
// Padded stride 40 u16: frag reads 2-way (free), staging writes <=3-way.
// Qo: [b,h,s,dk] * QSCALE;  Ko: [b,h,s,dk];  Vo: [b,h,s/4,dk,4]
__global__ __launch_bounds__(256, 3) void gemm_qkv(const u16* __restrict__ A,
                                                   const u16* __restrict__ Bt,
                                                   u16* __restrict__ Qo,
                                                   u16* __restrict__ Ko,
                                                   u16* __restrict__ Vo) {
  __shared__ __align__(16) u16 As[128 * 40];
  __shared__ __align__(16) u16 Bs[128 * 40];
  const int tid  = threadIdx.x;
  const int lane = tid & 63, wv = tid >> 6;
  const int wm   = wv >> 1, wn = wv & 1;
  const int lrow = lane & 15, quad = lane >> 4;
  const int tileM = blockIdx.x * 128, tileN = blockIdx.y * 128;
  const int r0 = tid >> 2, c0 = (tid & 3) * 8;   // staging: 2 chunks/thread per matrix
  const int r1 = r0 + 64;

  const f32x4 fz = {0.f, 0.f, 0.f, 0.f};
  f32x4 acc[4][4];
  #pragma unroll
  for (int i = 0; i < 4; ++i)
    #pragma unroll
    for (int j = 0; j < 4; ++j) acc[i][j] = fz;

  // prefetch tile kt=0
  uint4 a0 = *(const uint4*)(&A [(size_t)(tileM + r0) * DMOD + c0]);
  uint4 a1 = *(const uint4*)(&A [(size_t)(tileM + r1) * DMOD + c0]);
  uint4 b0 = *(const uint4*)(&Bt[(size_t)(tileN + r0) * DMOD + c0]);
  uint4 b1 = *(const uint4*)(&Bt[(size_t)(tileN + r1) * DMOD + c0]);

  for (int kt = 0; kt < DMOD; kt += 32) {
    __syncthreads();   // previous compute done reading LDS
    *(uint4*)(&As[r0 * 40 + c0]) = a0;
    *(uint4*)(&As[r1 * 40 + c0]) = a1;
    *(uint4*)(&Bs[r0 * 40 + c0]) = b0;
    *(uint4*)(&Bs[r1 * 40 + c0]) = b1;
    if (kt + 32 < DMOD) {
      a0 = *(const uint4*)(&A [(size_t)(tileM + r0) * DMOD + kt + 32 + c0]);
      a1 = *(const uint4*)(&A [(size_t)(tileM + r1) * DMOD + kt + 32 + c0]);
      b0 = *(const uint4*)(&Bt[(size_t)(tileN + r0) * DMOD + kt + 32 + c0]);
      b1 = *(const uint4*)(&Bt[(size_t)(tileN + r1) * DMOD + kt + 32 + c0]);
    }
    __syncthreads();   // tile visible
    bf16x8 af[4], bfr[4];
    #pragma unroll
    for (int mt = 0; mt < 4; ++mt)
      af[mt] = *(const bf16x8*)(&As[(wm * 64 + mt * 16 + lrow) * 40 + quad * 8]);
    #pragma unroll
    for (int nt = 0; nt < 4; ++nt)
      bfr[nt] = *(const bf16x8*)(&Bs[(wn * 64 + nt * 16 + lrow) * 40 + quad * 8]);
    #pragma unroll
    for (int mt = 0; mt < 4; ++mt)
      #pragma unroll
      for (int nt = 0; nt < 4; ++nt)
        acc[mt][nt] = __builtin_amdgcn_mfma_f32_16x16x32_bf16(af[mt], bfr[nt],
                                                              acc[mt][nt], 0, 0, 0);
  }

  #pragma unroll
  for (int mt = 0; mt < 4; ++mt) {
    #pragma unroll
    for (int nt = 0; nt < 4; ++nt) {
      int gm0 = tileM + wm * 64 + mt * 16 + quad * 4;
      int gn  = tileN + wn * 64 + nt * 16 + lrow;
      int which = gn >> 10, col = gn & 1023;
      int bb = gm0 >> 11, srw0 = gm0 & (SEQ - 1);
      int hh = col >> 6, dki = col & (DKH - 1);
      size_t bhi = (size_t)(bb * NH + hh);
      if (which == 0) {
        #pragma unroll
        for (int r = 0; r < 4; ++r)
          Qo[(bhi * SEQ + srw0 + r) * DKH + dki] = f2bf(acc[mt][nt][r] * QSCALE);
      } else if (which == 1) {
        #pragma unroll
        for (int r = 0; r < 4; ++r)
          Ko[(bhi * SEQ + srw0 + r) * DKH + dki] = f2bf(acc[mt][nt][r]);
      } else {
        uint2 pk;
        pk.x = pack2bf(acc[mt][nt][0], acc[mt][nt][1]);
        pk.y = pack2bf(acc[mt][nt][2], acc[mt][nt][3]);
        *(uint2*)(&Vo[(((bhi * (SEQ / 4)) + (srw0 >> 2)) * DKH + dki) * 4]) = pk;
      }
    }
  }
}

// -------- out GEMM: [4096x1024]*[1024x1024]^T -> fp32, 128x64, BK=32, reg-prefetch -----
__global__ __launch_bounds__(256, 3) void gemm_out(const u16* __restrict__ A,
                                                   const u16* __restrict__ Bt,
                                                   float* __restrict__ Co) {
  __shared__ __align__(16) u16 As[128 * 40];
  __shared__ __align__(16) u16 Bs[64 * 40];
  const int tid  = threadIdx.x;
  const int lane = tid & 63, wv = tid >> 6;
  const int wm   = wv & 1, wn = wv >> 1;
  const int lrow = lane & 15, quad = lane >> 4;
  const int tileM = blockIdx.x * 128, tileN = blockIdx.y * 64;
  const int r0 = tid >> 2, c0 = (tid & 3) * 8;
  const int r1 = r0 + 64;

  const f32x4 fz = {0.f, 0.f, 0.f, 0.f};
  f32x4 acc[4][2];
  #pragma unroll
  for (int i = 0; i < 4; ++i) { acc[i][0] = fz; acc[i][1] = fz; }

  uint4 a0 = *(const uint4*)(&A [(size_t)(tileM + r0) * DMOD + c0]);
  uint4 a1 = *(const uint4*)(&A [(size_t)(tileM + r1) * DMOD + c0]);
  uint4 b0 = *(const uint4*)(&Bt[(size_t)(tileN + (r0 & 63)) * DMOD + c0]);

  for (int kt = 0; kt < DMOD; kt += 32) {
    __syncthreads();
    *(uint4*)(&As[r0 * 40 + c0]) = a0;
    *(uint4*)(&As[r1 * 40 + c0]) = a1;
    if (r0 < 64) *(uint4*)(&Bs[r0 * 40 + c0]) = b0;
    if (kt + 32 < DMOD) {
      a0 = *(const uint4*)(&A [(size_t)(tileM + r0) * DMOD + kt + 32 + c0]);
      a1 = *(const uint4*)(&A [(size_t)(tileM + r1) * DMOD + kt + 32 + c0]);
      b0 = *(const uint4*)(&Bt[(size_t)(tileN + (r0 & 63)) * DMOD + kt + 32 + c0]);
    }
    __syncthreads();
    bf16x8 af[4], bfr[2];
    #pragma unroll
    for (int mt = 0; mt < 4; ++mt)
      af[mt] = *(const bf16x8*)(&As[(wm * 64 + mt * 16 + lrow) * 40 + quad * 8]);
    #pragma unroll
    for (int nt = 0; nt < 2; ++nt)
      bfr[nt] = *(const bf16x8*)(&Bs[(wn * 32 + nt * 16 + lrow) * 40 + quad * 8]);
    #pragma unroll
    for (int mt = 0; mt < 4; ++mt)
      #pragma unroll
      for (int nt = 0; nt < 2; ++nt)
        acc[mt][nt] = __builtin_amdgcn_mfma_f32_16x16x32_bf16(af[mt], bfr[nt],
                                                              acc[mt][nt], 0, 0, 0);
  }

  #pragma unroll
  for (int mt = 0; mt < 4; ++mt)
    #pragma unroll
    for (int nt = 0; nt < 2; ++nt)
      #pragma unroll
      for (int r = 0; r < 4; ++r) {
        int gm = tileM + wm * 64 + mt * 16 + quad * 4 + r;
        int gn = tileN + wn * 32 + nt * 16 + lrow;
        Co[(size_t)gm * DMOD + gn] = acc[mt][nt][r];
      }
}

// ---------------- causal flash attention: S^T form, LDS-double-buffered K/V ----------------
// (round-8 structure, best measured) grid (32 bh, 8 pairs); block 512 = 8 waves;
// q-tiles {p, 15-p} (17 j-iters, balanced). ONE barrier per j-iter; diagonal peeled.
#define KP 72
#define VP 132
#define OP 72

__global__ __launch_bounds__(512) void attn_k(const u16* __restrict__ Q,
                                              const u16* __restrict__ Kg,
                                              const u16* __restrict__ Vg,
                                              u16* __restrict__ Og) {
  __shared__ __align__(16) u16 KsA[128 * KP];
  __shared__ __align__(16) u16 VsA[64 * VP];
  __shared__ __align__(16) u16 KsB[128 * KP];
  __shared__ __align__(16) u16 VsB[64 * VP];
  __shared__ __align__(16) u16 Os[128 * OP];

  const int tid  = threadIdx.x;
  const int lane = tid & 63, w = tid >> 6;
  const int lrow = lane & 15, quad = lane >> 4;
  const int bh = blockIdx.x, pr = blockIdx.y;
  const int b = bh >> 4, h = bh & 15;

  const u16* Qbh = Q  + (size_t)bh * SEQ * DKH;
  const u16* Kbh = Kg + (size_t)bh * SEQ * DKH;
  const u16* Vbh = Vg + (size_t)bh * SEQ * DKH;   // [s/4][dk][4]

  uint4 kreg[2], vreg[2];
  #pragma unroll
  for (int k = 0; k < 2; ++k) {
    int ci = k * 512 + tid;
    kreg[k] = *(const uint4*)(&Kbh[(size_t)(ci >> 3) * DKH + (ci & 7) * 8]);
    vreg[k] = *(const uint4*)(&Vbh[(size_t)(ci >> 5) * 256 + (ci & 31) * 8]);
  }

  int cur = 0;
  const f32x4 fz = {0.f, 0.f, 0.f, 0.f};

  for (int half = 0; half < 2; ++half) {
    const int qt = half ? (15 - pr) : pr;
    const int jmax = qt;
    const int qglob = qt * 128 + w * 16 + lrow;

    bf16x8 bq[2];
    #pragma unroll
    for (int kk = 0; kk < 2; ++kk)
      bq[kk] = *(const bf16x8*)(&Qbh[(size_t)qglob * DKH + kk * 32 + quad * 8]);

    f32x4 oacc[4];
    #pragma unroll
    for (int d = 0; d < 4; ++d) oacc[d] = fz;
    float lsum = 0.f;

    for (int j = 0; j <= jmax; ++j) {
      u16* Ks = cur ? KsB : KsA;
      u16* Vs = cur ? VsB : VsA;

      #pragma unroll
      for (int k = 0; k < 2; ++k) {
        int ci = k * 512 + tid;
        *(uint4*)(&Ks[(ci >> 3) * KP + (ci & 7) * 8]) = kreg[k];
        int sq = ci >> 5, dkp = ci & 31;
        union { uint4 q; uint2 d[2]; } vv; vv.q = vreg[k];
        *(uint2*)(&Vs[(2 * dkp)     * VP + 4 * sq]) = vv.d[0];
        *(uint2*)(&Vs[(2 * dkp + 1) * VP + 4 * sq]) = vv.d[1];
      }

      const bool pf = (j < jmax) || (half == 0);
      if (pf) {
        const int jn = (j < jmax) ? (j + 1) : 0;
        #pragma unroll
        for (int k = 0; k < 2; ++k) {
          int ci = k * 512 + tid;
          kreg[k] = *(const uint4*)(&Kbh[(size_t)(jn * 128 + (ci >> 3)) * DKH + (ci & 7) * 8]);
          vreg[k] = *(const uint4*)(&Vbh[(size_t)(jn * 32 + (ci >> 5)) * 256 + (ci & 31) * 8]);
        }
      }

      __syncthreads();

      if (j < jmax) {
        f32x4 sacc[8];
        #pragma unroll
        for (int m = 0; m < 8; ++m) sacc[m] = fz;
        #pragma unroll
        for (int kk = 0; kk < 2; ++kk)
          #pragma unroll
          for (int m = 0; m < 8; ++m) {
            bf16x8 ak = *(const bf16x8*)(&Ks[(m * 16 + lrow) * KP + kk * 32 + quad * 8]);
            sacc[m] = __builtin_amdgcn_mfma_f32_16x16x32_bf16(ak, bq[kk], sacc[m], 0, 0, 0);
          }
        #pragma unroll
        for (int m = 0; m < 8; ++m)
          #pragma unroll
          for (int r = 0; r < 4; ++r) {
            float p = EXP2(sacc[m][r]);
            sacc[m][r] = p;
            lsum += p;
          }
        #pragma unroll
        for (int m = 0; m < 8; ++m) {
          union { u32 u[2]; s16x4 v; } pk;
          pk.u[0] = pack2bf(sacc[m][0], sacc[m][1]);
          pk.u[1] = pack2bf(sacc[m][2], sacc[m][3]);
          #pragma unroll
          for (int d = 0; d < 4; ++d) {
            s16x4 av = *(const s16x4*)(&Vs[(d * 16 + lrow) * VP + m * 16 + quad * 4]);
            oacc[d] = mfma16(av, pk.v, oacc[d]);
          }
        }
      } else {
        for (int m = 0; m < w; ++m) {
          f32x4 s = fz;
          #pragma unroll
          for (int kk = 0; kk < 2; ++kk) {
            bf16x8 ak = *(const bf16x8*)(&Ks[(m * 16 + lrow) * KP + kk * 32 + quad * 8]);
            s = __builtin_amdgcn_mfma_f32_16x16x32_bf16(ak, bq[kk], s, 0, 0, 0);
          }
          union { u32 u[2]; s16x4 v; } pk;
          float p0 = EXP2(s[0]), p1 = EXP2(s[1]), p2 = EXP2(s[2]), p3 = EXP2(s[3]);
          lsum += (p0 + p1) + (p2 + p3);
          pk.u[0] = pack2bf(p0, p1);
          pk.u[1] = pack2bf(p2, p3);
          #pragma unroll
          for (int d = 0; d < 4; ++d) {
            s16x4 av = *(const s16x4*)(&Vs[(d * 16 + lrow) * VP + m * 16 + quad * 4]);
            oacc[d] = mfma16(av, pk.v, oacc[d]);
          }
        }
        {
          f32x4 s = fz;
          #pragma unroll
          for (int kk = 0; kk < 2; ++kk) {
            bf16x8 ak = *(const bf16x8*)(&Ks[(w * 16 + lrow) * KP + kk * 32 + quad * 8]);
            s = __builtin_amdgcn_mfma_f32_16x16x32_bf16(ak, bq[kk], s, 0, 0, 0);
          }
          float p[4];
          #pragma unroll
          for (int r = 0; r < 4; ++r) {
            int kg = jmax * 128 + w * 16 + quad * 4 + r;
            p[r] = (kg > qglob) ? 0.f : EXP2(s[r]);
            lsum += p[r];
          }
          union { u32 u[2]; s16x4 v; } pk;
          pk.u[0] = pack2bf(p[0], p[1]);
          pk.u[1] = pack2bf(p[2], p[3]);
          #pragma unroll
          for (int d = 0; d < 4; ++d) {
            s16x4 av = *(const s16x4*)(&Vs[(d * 16 + lrow) * VP + w * 16 + quad * 4]);
            oacc[d] = mfma16(av, pk.v, oacc[d]);
          }
        }
      }
      cur ^= 1;
    }

    float ls = lsum;
    ls += __shfl_xor(ls, 16, 64);
    ls += __shfl_xor(ls, 32, 64);
    float inv = 1.f / ls;

    #pragma unroll
    for (int d = 0; d < 4; ++d) {
      uint2 pk;
      pk.x = pack2bf(oacc[d][0] * inv, oacc[d][1] * inv);
      pk.y = pack2bf(oacc[d][2] * inv, oacc[d][3] * inv);
      *(uint2*)(&Os[(w * 16 + lrow) * OP + d * 16 + quad * 4]) = pk;
    }
    __syncthreads();
    #pragma unroll
    for (int k = 0; k < 2; ++k) {
      int c = k * 512 + tid;
      int row = c >> 3, ch = c & 7;
      uint4 v = *(const uint4*)(&Os[row * OP + ch * 8]);
      *(uint4*)(&Og[(size_t)(b * SEQ + qt * 128 + row) * DMOD + h * DKH + ch * 8]) = v;
    }
    __syncthreads();
  }
}

// ---------------- launch ----------------
extern "C" void kernel_launch(void* const* d_in, const int* in_sizes, int n_in,
                              void* d_out, int out_size, void* d_ws, size_t ws_size,
                              hipStream_t stream) {
  const float* x  = (const float*)d_in[0];
  const float* Wq = (const float*)d_in[1];
  const float* Wk = (const float*)d_in[2];
  const float* Wv = (const float*)d_in[3];
  const float* Wo = (const float*)d_in[4];

  u16* ws = (u16*)d_ws;
  const size_t WSZ = (size_t)DMOD * DMOD;
  const size_t TSZ = (size_t)BAT * NH * SEQ * DKH;
  u16* Wt  = ws;                 // 4 transposed weights
  u16* Wto = Wt + 3 * WSZ;
  u16* xb  = Wt + 4 * WSZ;       // x bf16; dead after QKV -> reused as Ob
  u16* Qb  = xb + TSZ;
  u16* Kb  = Qb + TSZ;
  u16* Vb  = Kb + TSZ;           // [b,h,s/4,dk,4]
  u16* Ob  = xb;

  transpose_all<<<dim3(32, 32, 4), dim3(32, 8), 0, stream>>>(Wq, Wk, Wv, Wo, Wt);
  convert_x<<<dim3(2048), 256, 0, stream>>>(x, xb);

  gemm_qkv<<<dim3(32, 24), 256, 0, stream>>>(xb, Wt, Qb, Kb, Vb);

  attn_k<<<dim3(32, 8), 512, 0, stream>>>(Qb, Kb, Vb, Ob);

  gemm_out<<<dim3(32, 16), 256, 0, stream>>>(Ob, Wto, (float*)d_out);
}